// Round 10
// baseline (1701.044 us; speedup 1.0000x reference)
//
#include <hip/hip_runtime.h>

#define N_NODES 500000
#define N_EDGES 8000000
#define N_GRAPHS 4096

#define NB 3907          // ceil(500000/128) bins of 128 cols each
#define NBP 4096         // padded histogram stride
#define NW 64            // partition workgroups
#define CHUNK 125000     // N_EDGES / NW exactly
#define WFX_SCALE 33554432.0f   // 2^25 fixed-point for weight sums (max ~60*2^25 < 2^32)
#define WFX_INV (1.0 / 33554432.0)

// ---------------- pass A: per-workgroup LDS bin histogram (no global atomics) ------

__global__ void k_binA(const int* __restrict__ col, unsigned* __restrict__ hists) {
    __shared__ unsigned h[NBP];
    int tid = threadIdx.x, wg = blockIdx.x;
    for (int b = tid; b < NBP; b += 256) h[b] = 0;
    __syncthreads();
    int s = wg * CHUNK, t = s + CHUNK;
    for (int e = s + tid; e < t; e += 256)
        atomicAdd(&h[col[e] >> 7], 1u);
    __syncthreads();
    for (int b = tid; b < NBP; b += 256) hists[(size_t)wg * NBP + b] = h[b];
}

// ---------------- pass B: bin scan -> binptr + per-(bin,wg) start offsets ----------
// single workgroup of 1024; thread owns 4 bins.

__global__ void k_binB(const unsigned* __restrict__ hists, int* __restrict__ binptr,
                       unsigned* __restrict__ wgoff) {
    __shared__ unsigned sh[1024];
    int tid = threadIdx.x;
    int b0 = tid * 4;
    unsigned tot = 0;
    for (int j = 0; j < 4; j++) {
        int b = b0 + j;
        unsigned s = 0;
        if (b < NB)
            for (int w = 0; w < NW; w++) s += hists[(size_t)w * NBP + b];
        tot += s;
    }
    sh[tid] = tot;
    __syncthreads();
    for (int off = 1; off < 1024; off <<= 1) {
        unsigned v = (tid >= off) ? sh[tid - off] : 0;
        __syncthreads();
        sh[tid] += v;
        __syncthreads();
    }
    unsigned run = (tid == 0) ? 0 : sh[tid - 1];
    for (int j = 0; j < 4; j++) {
        int b = b0 + j;
        if (b < NB) {
            binptr[b] = (int)run;
            for (int w = 0; w < NW; w++) {
                wgoff[(size_t)b * NW + w] = run;
                run += hists[(size_t)w * NBP + b];
            }
        }
    }
    if (tid == 0) binptr[NB] = N_EDGES;
}

// ---------------- pass C: partition edges into bin slices (disjoint, race-free) ----

__global__ void k_binC(const int* __restrict__ row, const int* __restrict__ col,
                       const float* __restrict__ w, const unsigned* __restrict__ wgoff,
                       uint4* __restrict__ tmp4) {
    __shared__ unsigned loff[NBP];
    int tid = threadIdx.x, wg = blockIdx.x;
    for (int b = tid; b < NB; b += 256) loff[b] = wgoff[(size_t)b * NW + wg];
    __syncthreads();
    int s = wg * CHUNK, t = s + CHUNK;
    for (int e = s + tid; e < t; e += 256) {
        int c = col[e];
        unsigned pos = atomicAdd(&loff[c >> 7], 1u);  // LDS atomic
        tmp4[pos] = make_uint4((unsigned)c, (unsigned)row[e], __float_as_uint(w[e]), 0u);
    }
}

// ---------------- pass D1: per-bin counts + weighted degree -> dinv, rowptr --------

__global__ void k_binD1(const uint4* __restrict__ tmp4, const int* __restrict__ binptr,
                        float* __restrict__ dinv, int* __restrict__ rowptr) {
    __shared__ unsigned cnt[128], wfx[128], sc[128];
    int b = blockIdx.x, tid = threadIdx.x;
    int c0 = b << 7;
    int ncol = min(128, N_NODES - c0);
    if (tid < 128) { cnt[tid] = 0; wfx[tid] = 0; }
    __syncthreads();
    int s = binptr[b], t = binptr[b + 1];
    for (int i = s + tid; i < t; i += 256) {
        uint4 r = tmp4[i];
        int lc = (int)r.x & 127;
        atomicAdd(&cnt[lc], 1u);
        unsigned wf = (unsigned)(__uint_as_float(r.z) * WFX_SCALE + 0.5f);
        atomicAdd(&wfx[lc], wf);
    }
    __syncthreads();
    if (tid < 128) sc[tid] = cnt[tid];
    __syncthreads();
    for (int off = 1; off < 128; off <<= 1) {
        unsigned v = (tid < 128 && tid >= off) ? sc[tid - off] : 0;
        __syncthreads();
        if (tid < 128) sc[tid] += v;
        __syncthreads();
    }
    if (tid < ncol) {
        float deg = (float)(1.0 + (double)wfx[tid] * WFX_INV);  // self-loop weight 1
        dinv[c0 + tid] = rsqrtf(deg);
        int excl = (tid == 0) ? 0 : (int)sc[tid - 1];
        rowptr[c0 + tid] = s + excl;
    }
    if (b == NB - 1 && tid == 0) rowptr[N_NODES] = N_EDGES;
}

// ---------------- pass D2: place {norm,row} records (dinv complete) ----------------

__global__ void k_binD2(const uint4* __restrict__ tmp4, const int* __restrict__ binptr,
                        const int* __restrict__ rowptr, const float* __restrict__ dinv,
                        float2* __restrict__ ebuf) {
    __shared__ unsigned cur[128];
    __shared__ float dl[128];
    int b = blockIdx.x, tid = threadIdx.x;
    int c0 = b << 7;
    int ncol = min(128, N_NODES - c0);
    if (tid < ncol) { cur[tid] = (unsigned)rowptr[c0 + tid]; dl[tid] = dinv[c0 + tid]; }
    __syncthreads();
    int s = binptr[b], t = binptr[b + 1];
    for (int i = s + tid; i < t; i += 256) {
        uint4 r = tmp4[i];
        int lc = (int)r.x & 127;
        unsigned pos = atomicAdd(&cur[lc], 1u);  // LDS cursor
        float nv = __uint_as_float(r.z) * dinv[r.y] * dl[lc];
        ebuf[pos] = make_float2(nv, __int_as_float((int)r.y));
    }
}

// ---------------- graph boundaries (batch is sorted) ----------------

__global__ void k_gstart(const int* __restrict__ batch, int* __restrict__ gstart) {
    int g = blockIdx.x * blockDim.x + threadIdx.x;
    if (g > N_GRAPHS) return;
    if (g == N_GRAPHS) { gstart[g] = N_NODES; return; }
    int lo = 0, hi = N_NODES;
    while (lo < hi) {
        int mid = (lo + hi) >> 1;
        if (batch[mid] < g) lo = mid + 1; else hi = mid;
    }
    gstart[g] = lo;
}

// ---------------- xw1 = x @ W1  (9 -> 8) ----------------

__global__ void k_mm1(const float* __restrict__ x, const float* __restrict__ W,
                      float* __restrict__ out) {
    int i = blockIdx.x * blockDim.x + threadIdx.x;
    if (i >= N_NODES) return;
    float xi[9];
#pragma unroll
    for (int f = 0; f < 9; f++) xi[f] = x[i * 9 + f];
    float o[8];
#pragma unroll
    for (int fo = 0; fo < 8; fo++) o[fo] = 0.0f;
#pragma unroll
    for (int fi = 0; fi < 9; fi++) {
        float a = xi[fi];
#pragma unroll
        for (int fo = 0; fo < 8; fo++) o[fo] += a * W[fi * 8 + fo];
    }
    float4* po = reinterpret_cast<float4*>(out + i * 8);
    po[0] = make_float4(o[0], o[1], o[2], o[3]);
    po[1] = make_float4(o[4], o[5], o[6], o[7]);
}

// ---------------- gather-reduce (unchanged) ----------------

template <int LOGF, bool RELU>
__global__ void k_gather(const int* __restrict__ rowptr, const float2* __restrict__ ebuf,
                         const float* __restrict__ dinv, const float* __restrict__ xw,
                         float* __restrict__ outb, const float* __restrict__ bias) {
    const int F = 1 << LOGF;
    int t = blockIdx.x * blockDim.x + threadIdx.x;
    int c = t >> LOGF;
    if (c >= N_NODES) return;
    int f = t & (F - 1);
    float d = dinv[c];
    float acc = d * d * xw[(c << LOGF) + f];
    int e0 = rowptr[c], e1 = rowptr[c + 1];
#pragma unroll 2
    for (int e = e0; e < e1; e++) {
        float2 rn = ebuf[e];
        int r = __float_as_int(rn.y);
        acc += rn.x * xw[(r << LOGF) + f];
    }
    if (RELU) acc = fmaxf(acc + bias[f], 0.0f);
    outb[t] = acc;
}

// ---------------- h2 = relu(agg2 @ W2 + b2)   (8 -> 16) ----------------

__global__ void k_mm2(const float* __restrict__ hin, const float* __restrict__ W,
                      const float* __restrict__ b, float* __restrict__ hout) {
    int i = blockIdx.x * blockDim.x + threadIdx.x;
    if (i >= N_NODES) return;
    float a[8];
    const float4* p = reinterpret_cast<const float4*>(hin + i * 8);
#pragma unroll
    for (int q = 0; q < 2; q++) {
        float4 v = p[q];
        a[q * 4 + 0] = v.x; a[q * 4 + 1] = v.y; a[q * 4 + 2] = v.z; a[q * 4 + 3] = v.w;
    }
    float o[16];
#pragma unroll
    for (int fo = 0; fo < 16; fo++) o[fo] = b[fo];
#pragma unroll
    for (int fi = 0; fi < 8; fi++) {
        float av = a[fi];
#pragma unroll
        for (int fo = 0; fo < 16; fo++) o[fo] += av * W[fi * 16 + fo];
    }
    float4* po = reinterpret_cast<float4*>(hout + i * 16);
#pragma unroll
    for (int q = 0; q < 4; q++)
        po[q] = make_float4(fmaxf(o[q * 4 + 0], 0.0f), fmaxf(o[q * 4 + 1], 0.0f),
                            fmaxf(o[q * 4 + 2], 0.0f), fmaxf(o[q * 4 + 3], 0.0f));
}

// ---------------- pooling over agg3 (16-dim) ----------------

__global__ void k_pool2(const float* __restrict__ h, const int* __restrict__ gstart,
                        float* __restrict__ psum) {
    int t = blockIdx.x * blockDim.x + threadIdx.x;
    if (t >= (N_GRAPHS << 4)) return;
    int g = t >> 4;
    int f = t & 15;
    int s = gstart[g], e = gstart[g + 1];
    float acc = 0.0f;
    for (int i = s; i < e; i++) acc += h[(i << 4) + f];
    psum[t] = acc;
}

// out[g] = ((mean agg3) @ W3 + b3) @ Wl + bl

__global__ void k_final(const float* __restrict__ psum, const int* __restrict__ gstart,
                        const float* __restrict__ W3, const float* __restrict__ b3,
                        const float* __restrict__ Wl, const float* __restrict__ bl,
                        float* __restrict__ out) {
    int g = blockIdx.x * blockDim.x + threadIdx.x;
    if (g >= N_GRAPHS) return;
    int cnt = gstart[g + 1] - gstart[g];
    float o0 = bl[0], o1 = bl[1];
    if (cnt > 0) {
        float inv = 1.0f / (float)cnt;
        float p[16];
#pragma unroll
        for (int k = 0; k < 16; k++) p[k] = psum[(g << 4) + k] * inv;
#pragma unroll
        for (int fo = 0; fo < 32; fo++) {
            float t = b3[fo];
#pragma unroll
            for (int k = 0; k < 16; k++) t += p[k] * W3[k * 32 + fo];
            o0 += t * Wl[fo * 2 + 0];
            o1 += t * Wl[fo * 2 + 1];
        }
    }
    out[g * 2 + 0] = o0;
    out[g * 2 + 1] = o1;
}

// ---------------- launch ----------------

static inline int nblk(long n, int b) { return (int)((n + b - 1) / b); }

extern "C" void kernel_launch(void* const* d_in, const int* in_sizes, int n_in,
                              void* d_out, int out_size, void* d_ws, size_t ws_size,
                              hipStream_t stream) {
    const float* x     = (const float*)d_in[0];
    const int*   ei    = (const int*)d_in[1];
    const float* ew    = (const float*)d_in[2];
    const int*   batch = (const int*)d_in[3];
    const float* W1 = (const float*)d_in[4];
    const float* b1 = (const float*)d_in[5];
    const float* W2 = (const float*)d_in[6];
    const float* b2 = (const float*)d_in[7];
    const float* W3 = (const float*)d_in[8];
    const float* b3 = (const float*)d_in[9];
    const float* Wl = (const float*)d_in[10];
    const float* bl = (const float*)d_in[11];
    float* out = (float*)d_out;

    const int* row = ei;            // edge_index[0]
    const int* col = ei + N_EDGES;  // edge_index[1]

    // workspace layout (float offsets; all 16B aligned)
    float*    dinv   = (float*)d_ws;                 // [0, 500224)
    int*      rowptr = (int*)(dinv + 500224);        // [500224, 1000448)
    int*      binptr = (int*)(dinv + 1000448);       // [1000448, 1004544)  NB+1 used
    unsigned* hists  = (unsigned*)(dinv + 1004544);  // [1004544, 1266688)  64*4096
    unsigned* wgoff  = (unsigned*)(dinv + 1266688);  // [1266688, 1528832)  3907*64
    float2*   ebuf   = (float2*)(dinv + 1528832);    // [1528832, 17528832) 8M float2
    float*    bufA   = dinv + 17528832;              // [17528832, 33528832) 16M
    float*    bufB   = dinv + 33528832;              // [33528832, 49528832) 16M
    int*      gstart = (int*)(dinv + 49528832);      // 4104
    float*    psum   = dinv + 49532936;              // 65536   (end ~198.4 MB)

    uint4* tmp4 = (uint4*)bufA;  // 8M uint4 = 128MB aliases bufA+bufB (dead after D2)

    const int B = 256;

    // binned CSR build: zero global atomics
    k_binA<<<NW, B, 0, stream>>>(col, hists);
    k_binB<<<1, 1024, 0, stream>>>(hists, binptr, wgoff);
    k_binC<<<NW, B, 0, stream>>>(row, col, ew, wgoff, tmp4);
    k_binD1<<<NB, B, 0, stream>>>(tmp4, binptr, dinv, rowptr);
    k_binD2<<<NB, B, 0, stream>>>(tmp4, binptr, rowptr, dinv, ebuf);
    k_gstart<<<nblk(N_GRAPHS + 1, B), B, 0, stream>>>(batch, gstart);

    // layer 1: xw1 (after D2: bufA free), then h1 = relu(A @ xw1 + b1) at F=8
    k_mm1<<<nblk(N_NODES, B), B, 0, stream>>>(x, W1, bufA);
    k_gather<3, true><<<nblk((long)N_NODES * 8, B), B, 0, stream>>>(rowptr, ebuf, dinv, bufA, bufB, b1);

    // layer 2: agg2 = A @ h1 (F=8), then h2 = relu(agg2 @ W2 + b2)
    k_gather<3, false><<<nblk((long)N_NODES * 8, B), B, 0, stream>>>(rowptr, ebuf, dinv, bufB, bufA, nullptr);
    k_mm2<<<nblk(N_NODES, B), B, 0, stream>>>(bufA, W2, b2, bufB);

    // layer 3: agg3 = A @ h2 (F=16); W3+b3 post-pool
    k_gather<4, false><<<nblk((long)N_NODES * 16, B), B, 0, stream>>>(rowptr, ebuf, dinv, bufB, bufA, nullptr);

    // pool agg3 (16-dim) + fused W3/b3/classifier
    k_pool2<<<nblk((long)N_GRAPHS * 16, B), B, 0, stream>>>(bufA, gstart, psum);
    k_final<<<nblk(N_GRAPHS, B), B, 0, stream>>>(psum, gstart, W3, b3, Wl, bl, out);
}

// Round 14
// 1052.633 us; speedup vs baseline: 1.6160x; 1.6160x over previous
//
#include <hip/hip_runtime.h>

#define N_NODES 500000
#define N_EDGES 8000000
#define N_GRAPHS 4096

#define NB 3907          // ceil(500000/128) bins of 128 cols each
#define NBP 4096         // padded histogram stride
#define NW 1000          // partition workgroups (N_EDGES/NW = 8000 exactly)
#define CHUNK 8000
#define WFX_SCALE 33554432.0f   // 2^25 fixed-point for weight sums
#define WFX_INV (1.0 / 33554432.0)

// ---------------- pass A: per-workgroup LDS bin histogram (no global atomics) ------

__global__ void k_binA(const int* __restrict__ col, unsigned* __restrict__ hists) {
    __shared__ unsigned h[NBP];
    int tid = threadIdx.x, wg = blockIdx.x;
    for (int b = tid; b < NBP; b += 256) h[b] = 0;
    __syncthreads();
    int s = wg * CHUNK, t = s + CHUNK;
    for (int e = s + tid; e < t; e += 256)
        atomicAdd(&h[col[e] >> 7], 1u);
    __syncthreads();
    for (int b = tid; b < NBP; b += 256) hists[(size_t)wg * NBP + b] = h[b];
}

// ---------------- pass B1: per-bin scan over the NW wg-counts (in place) -----------
// hists[w][b] <- exclusive prefix over w; bintot[b] = total.

__global__ void k_binB1(unsigned* __restrict__ hists, unsigned* __restrict__ bintot) {
    __shared__ unsigned sh[1024];
    int b = blockIdx.x, w = threadIdx.x;
    unsigned v = (w < NW) ? hists[(size_t)w * NBP + b] : 0;
    sh[w] = v;
    __syncthreads();
    for (int off = 1; off < 1024; off <<= 1) {
        unsigned t = (w >= off) ? sh[w - off] : 0;
        __syncthreads();
        sh[w] += t;
        __syncthreads();
    }
    if (w < NW) hists[(size_t)w * NBP + b] = sh[w] - v;  // exclusive
    if (w == 1023) bintot[b] = sh[1023];
}

// ---------------- pass B2: exclusive scan of bin totals -> binptr ------------------

__global__ void k_binB2(const unsigned* __restrict__ bintot, int* __restrict__ binptr) {
    __shared__ unsigned sh[1024];
    int tid = threadIdx.x;
    int b0 = tid * 4;
    unsigned v[4];
    unsigned tot = 0;
#pragma unroll
    for (int j = 0; j < 4; j++) {
        v[j] = (b0 + j < NB) ? bintot[b0 + j] : 0;
        tot += v[j];
    }
    sh[tid] = tot;
    __syncthreads();
    for (int off = 1; off < 1024; off <<= 1) {
        unsigned t = (tid >= off) ? sh[tid - off] : 0;
        __syncthreads();
        sh[tid] += t;
        __syncthreads();
    }
    unsigned run = (tid == 0) ? 0 : sh[tid - 1];
#pragma unroll
    for (int j = 0; j < 4; j++) {
        if (b0 + j < NB) binptr[b0 + j] = (int)run;
        run += v[j];
    }
    if (tid == 0) binptr[NB] = N_EDGES;
}

// ---------------- pass C: partition edges into bin slices (disjoint, race-free) ----

__global__ void k_binC(const int* __restrict__ row, const int* __restrict__ col,
                       const float* __restrict__ w, const unsigned* __restrict__ hists,
                       const int* __restrict__ binptr, uint4* __restrict__ tmp4) {
    __shared__ unsigned loff[NBP];
    int tid = threadIdx.x, wg = blockIdx.x;
    for (int b = tid; b < NB; b += 256)
        loff[b] = (unsigned)binptr[b] + hists[(size_t)wg * NBP + b];
    __syncthreads();
    int s = wg * CHUNK, t = s + CHUNK;
    for (int e = s + tid; e < t; e += 256) {
        int c = col[e];
        unsigned pos = atomicAdd(&loff[c >> 7], 1u);  // LDS atomic
        tmp4[pos] = make_uint4((unsigned)c, (unsigned)row[e], __float_as_uint(w[e]), 0u);
    }
}

// ---------------- pass D1: per-bin counts + weighted degree -> dinv, rowptr --------

__global__ void k_binD1(const uint4* __restrict__ tmp4, const int* __restrict__ binptr,
                        float* __restrict__ dinv, int* __restrict__ rowptr) {
    __shared__ unsigned cnt[128], wfx[128], sc[128];
    int b = blockIdx.x, tid = threadIdx.x;
    int c0 = b << 7;
    int ncol = min(128, N_NODES - c0);
    if (tid < 128) { cnt[tid] = 0; wfx[tid] = 0; }
    __syncthreads();
    int s = binptr[b], t = binptr[b + 1];
    for (int i = s + tid; i < t; i += 256) {
        uint4 r = tmp4[i];
        int lc = (int)r.x & 127;
        atomicAdd(&cnt[lc], 1u);
        unsigned wf = (unsigned)(__uint_as_float(r.z) * WFX_SCALE + 0.5f);
        atomicAdd(&wfx[lc], wf);
    }
    __syncthreads();
    if (tid < 128) sc[tid] = cnt[tid];
    __syncthreads();
    for (int off = 1; off < 128; off <<= 1) {
        unsigned v = (tid < 128 && tid >= off) ? sc[tid - off] : 0;
        __syncthreads();
        if (tid < 128) sc[tid] += v;
        __syncthreads();
    }
    if (tid < ncol) {
        float deg = (float)(1.0 + (double)wfx[tid] * WFX_INV);  // self-loop weight 1
        dinv[c0 + tid] = rsqrtf(deg);
        int excl = (tid == 0) ? 0 : (int)sc[tid - 1];
        rowptr[c0 + tid] = s + excl;
    }
    if (b == NB - 1 && tid == 0) rowptr[N_NODES] = N_EDGES;
}

// ---------------- pass D2: place {norm,row} records (dinv complete) ----------------

__global__ void k_binD2(const uint4* __restrict__ tmp4, const int* __restrict__ binptr,
                        const int* __restrict__ rowptr, const float* __restrict__ dinv,
                        float2* __restrict__ ebuf) {
    __shared__ unsigned cur[128];
    __shared__ float dl[128];
    int b = blockIdx.x, tid = threadIdx.x;
    int c0 = b << 7;
    int ncol = min(128, N_NODES - c0);
    if (tid < ncol) { cur[tid] = (unsigned)rowptr[c0 + tid]; dl[tid] = dinv[c0 + tid]; }
    __syncthreads();
    int s = binptr[b], t = binptr[b + 1];
    for (int i = s + tid; i < t; i += 256) {
        uint4 r = tmp4[i];
        int lc = (int)r.x & 127;
        unsigned pos = atomicAdd(&cur[lc], 1u);  // LDS cursor
        float nv = __uint_as_float(r.z) * dinv[r.y] * dl[lc];
        ebuf[pos] = make_float2(nv, __int_as_float((int)r.y));
    }
}

// ---------------- graph boundaries (batch is sorted) ----------------

__global__ void k_gstart(const int* __restrict__ batch, int* __restrict__ gstart) {
    int g = blockIdx.x * blockDim.x + threadIdx.x;
    if (g > N_GRAPHS) return;
    if (g == N_GRAPHS) { gstart[g] = N_NODES; return; }
    int lo = 0, hi = N_NODES;
    while (lo < hi) {
        int mid = (lo + hi) >> 1;
        if (batch[mid] < g) lo = mid + 1; else hi = mid;
    }
    gstart[g] = lo;
}

// ---------------- xw1 = x @ W1  (9 -> 8) ----------------

__global__ void k_mm1(const float* __restrict__ x, const float* __restrict__ W,
                      float* __restrict__ out) {
    int i = blockIdx.x * blockDim.x + threadIdx.x;
    if (i >= N_NODES) return;
    float xi[9];
#pragma unroll
    for (int f = 0; f < 9; f++) xi[f] = x[i * 9 + f];
    float o[8];
#pragma unroll
    for (int fo = 0; fo < 8; fo++) o[fo] = 0.0f;
#pragma unroll
    for (int fi = 0; fi < 9; fi++) {
        float a = xi[fi];
#pragma unroll
        for (int fo = 0; fo < 8; fo++) o[fo] += a * W[fi * 8 + fo];
    }
    float4* po = reinterpret_cast<float4*>(out + i * 8);
    po[0] = make_float4(o[0], o[1], o[2], o[3]);
    po[1] = make_float4(o[4], o[5], o[6], o[7]);
}

// ---------------- gather-reduce (unchanged) ----------------

template <int LOGF, bool RELU>
__global__ void k_gather(const int* __restrict__ rowptr, const float2* __restrict__ ebuf,
                         const float* __restrict__ dinv, const float* __restrict__ xw,
                         float* __restrict__ outb, const float* __restrict__ bias) {
    const int F = 1 << LOGF;
    int t = blockIdx.x * blockDim.x + threadIdx.x;
    int c = t >> LOGF;
    if (c >= N_NODES) return;
    int f = t & (F - 1);
    float d = dinv[c];
    float acc = d * d * xw[(c << LOGF) + f];
    int e0 = rowptr[c], e1 = rowptr[c + 1];
#pragma unroll 2
    for (int e = e0; e < e1; e++) {
        float2 rn = ebuf[e];
        int r = __float_as_int(rn.y);
        acc += rn.x * xw[(r << LOGF) + f];
    }
    if (RELU) acc = fmaxf(acc + bias[f], 0.0f);
    outb[t] = acc;
}

// ---------------- h2 = relu(agg2 @ W2 + b2)   (8 -> 16) ----------------

__global__ void k_mm2(const float* __restrict__ hin, const float* __restrict__ W,
                      const float* __restrict__ b, float* __restrict__ hout) {
    int i = blockIdx.x * blockDim.x + threadIdx.x;
    if (i >= N_NODES) return;
    float a[8];
    const float4* p = reinterpret_cast<const float4*>(hin + i * 8);
#pragma unroll
    for (int q = 0; q < 2; q++) {
        float4 v = p[q];
        a[q * 4 + 0] = v.x; a[q * 4 + 1] = v.y; a[q * 4 + 2] = v.z; a[q * 4 + 3] = v.w;
    }
    float o[16];
#pragma unroll
    for (int fo = 0; fo < 16; fo++) o[fo] = b[fo];
#pragma unroll
    for (int fi = 0; fi < 8; fi++) {
        float av = a[fi];
#pragma unroll
        for (int fo = 0; fo < 16; fo++) o[fo] += av * W[fi * 16 + fo];
    }
    float4* po = reinterpret_cast<float4*>(hout + i * 16);
#pragma unroll
    for (int q = 0; q < 4; q++)
        po[q] = make_float4(fmaxf(o[q * 4 + 0], 0.0f), fmaxf(o[q * 4 + 1], 0.0f),
                            fmaxf(o[q * 4 + 2], 0.0f), fmaxf(o[q * 4 + 3], 0.0f));
}

// ---------------- pooling over agg3 (16-dim) ----------------

__global__ void k_pool2(const float* __restrict__ h, const int* __restrict__ gstart,
                        float* __restrict__ psum) {
    int t = blockIdx.x * blockDim.x + threadIdx.x;
    if (t >= (N_GRAPHS << 4)) return;
    int g = t >> 4;
    int f = t & 15;
    int s = gstart[g], e = gstart[g + 1];
    float acc = 0.0f;
    for (int i = s; i < e; i++) acc += h[(i << 4) + f];
    psum[t] = acc;
}

// out[g] = ((mean agg3) @ W3 + b3) @ Wl + bl

__global__ void k_final(const float* __restrict__ psum, const int* __restrict__ gstart,
                        const float* __restrict__ W3, const float* __restrict__ b3,
                        const float* __restrict__ Wl, const float* __restrict__ bl,
                        float* __restrict__ out) {
    int g = blockIdx.x * blockDim.x + threadIdx.x;
    if (g >= N_GRAPHS) return;
    int cnt = gstart[g + 1] - gstart[g];
    float o0 = bl[0], o1 = bl[1];
    if (cnt > 0) {
        float inv = 1.0f / (float)cnt;
        float p[16];
#pragma unroll
        for (int k = 0; k < 16; k++) p[k] = psum[(g << 4) + k] * inv;
#pragma unroll
        for (int fo = 0; fo < 32; fo++) {
            float t = b3[fo];
#pragma unroll
            for (int k = 0; k < 16; k++) t += p[k] * W3[k * 32 + fo];
            o0 += t * Wl[fo * 2 + 0];
            o1 += t * Wl[fo * 2 + 1];
        }
    }
    out[g * 2 + 0] = o0;
    out[g * 2 + 1] = o1;
}

// ---------------- launch ----------------

static inline int nblk(long n, int b) { return (int)((n + b - 1) / b); }

extern "C" void kernel_launch(void* const* d_in, const int* in_sizes, int n_in,
                              void* d_out, int out_size, void* d_ws, size_t ws_size,
                              hipStream_t stream) {
    const float* x     = (const float*)d_in[0];
    const int*   ei    = (const int*)d_in[1];
    const float* ew    = (const float*)d_in[2];
    const int*   batch = (const int*)d_in[3];
    const float* W1 = (const float*)d_in[4];
    const float* b1 = (const float*)d_in[5];
    const float* W2 = (const float*)d_in[6];
    const float* b2 = (const float*)d_in[7];
    const float* W3 = (const float*)d_in[8];
    const float* b3 = (const float*)d_in[9];
    const float* Wl = (const float*)d_in[10];
    const float* bl = (const float*)d_in[11];
    float* out = (float*)d_out;

    const int* row = ei;            // edge_index[0]
    const int* col = ei + N_EDGES;  // edge_index[1]

    // workspace layout (float offsets; all 16B aligned)
    float*    dinv   = (float*)d_ws;                 // [0, 500224)
    int*      rowptr = (int*)(dinv + 500224);        // [500224, 1000448)
    int*      binptr = (int*)(dinv + 1000448);       // [1000448, 1004544)  NB+1 used
    unsigned* bintot = (unsigned*)(dinv + 1004544);  // [1004544, 1008640)
    float2*   ebuf   = (float2*)(dinv + 1008640);    // [1008640, 17008640) 8M float2
    float*    bufA   = dinv + 17008640;              // [17008640, 33008640) 16M
    float*    bufB   = dinv + 33008640;              // [33008640, 49008640) 16M
    int*      gstart = (int*)(dinv + 49008640);      // 4104
    float*    psum   = dinv + 49012744;              // 65536  (end ~196.3 MB)

    // hists (1000*4096 u32 = 16.4MB) aliases ebuf start: dead before D2 writes ebuf
    unsigned* hists = (unsigned*)ebuf;
    // tmp4 (8M uint4 = 128MB) aliases bufA+bufB: dead before mm1 writes bufA
    uint4* tmp4 = (uint4*)bufA;

    const int B = 256;

    // binned CSR build: zero global atomics, now with 1000-WG parallelism
    k_binA<<<NW, B, 0, stream>>>(col, hists);
    k_binB1<<<NB, 1024, 0, stream>>>(hists, bintot);
    k_binB2<<<1, 1024, 0, stream>>>(bintot, binptr);
    k_binC<<<NW, B, 0, stream>>>(row, col, ew, hists, binptr, tmp4);
    k_binD1<<<NB, B, 0, stream>>>(tmp4, binptr, dinv, rowptr);
    k_binD2<<<NB, B, 0, stream>>>(tmp4, binptr, rowptr, dinv, ebuf);
    k_gstart<<<nblk(N_GRAPHS + 1, B), B, 0, stream>>>(batch, gstart);

    // layer 1: xw1 (after D2: bufA free), then h1 = relu(A @ xw1 + b1) at F=8
    k_mm1<<<nblk(N_NODES, B), B, 0, stream>>>(x, W1, bufA);
    k_gather<3, true><<<nblk((long)N_NODES * 8, B), B, 0, stream>>>(rowptr, ebuf, dinv, bufA, bufB, b1);

    // layer 2: agg2 = A @ h1 (F=8), then h2 = relu(agg2 @ W2 + b2)
    k_gather<3, false><<<nblk((long)N_NODES * 8, B), B, 0, stream>>>(rowptr, ebuf, dinv, bufB, bufA, nullptr);
    k_mm2<<<nblk(N_NODES, B), B, 0, stream>>>(bufA, W2, b2, bufB);

    // layer 3: agg3 = A @ h2 (F=16); W3+b3 post-pool
    k_gather<4, false><<<nblk((long)N_NODES * 16, B), B, 0, stream>>>(rowptr, ebuf, dinv, bufB, bufA, nullptr);

    // pool agg3 (16-dim) + fused W3/b3/classifier
    k_pool2<<<nblk((long)N_GRAPHS * 16, B), B, 0, stream>>>(bufA, gstart, psum);
    k_final<<<nblk(N_GRAPHS, B), B, 0, stream>>>(psum, gstart, W3, b3, Wl, bl, out);
}